// Round 1
// baseline (226.791 us; speedup 1.0000x reference)
//
#include <hip/hip_runtime.h>

// Ragged gather-to-padded for SparseConvUnet preprocessing.
// feature: [Nrows=1.4M, 128] f32 packed; atom_num: [N] int32 in [0,14);
// out = concat( padded [N,14,128] f32 (zero where slot>=atom_num), label as f32 [N] ).

#define MAX_ATOMS 14
#define CCH 128
#define F4_PER_ROW 32                       // 128 floats = 32 float4
#define F4_PER_RES (MAX_ATOMS * F4_PER_ROW) // 448
#define RPB 16                              // residues per gather block

// ---- prefix-sum stage 1: per-256-residue block sums ----
__global__ void k_block_sums(const int* __restrict__ atom_num, int n,
                             int* __restrict__ sums) {
    __shared__ int lds[256];
    int t = threadIdx.x;
    int r = blockIdx.x * 256 + t;
    lds[t] = (r < n) ? atom_num[r] : 0;
    __syncthreads();
    for (int d = 128; d > 0; d >>= 1) {
        if (t < d) lds[t] += lds[t + d];
        __syncthreads();
    }
    if (t == 0) sums[blockIdx.x] = lds[0];
}

// ---- prefix-sum stage 2: single-block exclusive scan of block sums (nb<=512) ----
__global__ void k_scan_sums(int* __restrict__ sums, int nb) {
    __shared__ int lds[512];
    int t = threadIdx.x;
    int v = (t < nb) ? sums[t] : 0;
    lds[t] = v;
    __syncthreads();
    for (int d = 1; d < 512; d <<= 1) {
        int add = (t >= d) ? lds[t - d] : 0;
        __syncthreads();
        lds[t] += add;
        __syncthreads();
    }
    if (t < nb) sums[t] = lds[t] - v;  // exclusive
}

// ---- prefix-sum stage 3: per-residue exclusive offsets ----
__global__ void k_offsets(const int* __restrict__ atom_num, int n,
                          const int* __restrict__ scanned,
                          int* __restrict__ offsets) {
    __shared__ int lds[256];
    int t = threadIdx.x;
    int r = blockIdx.x * 256 + t;
    int v = (r < n) ? atom_num[r] : 0;
    lds[t] = v;
    __syncthreads();
    for (int d = 1; d < 256; d <<= 1) {
        int add = (t >= d) ? lds[t - d] : 0;
        __syncthreads();
        lds[t] += add;
        __syncthreads();
    }
    if (r < n) offsets[r] = scanned[blockIdx.x] + lds[t] - v;
}

// ---- main gather: RPB residues per block, float4 coalesced ----
__global__ void k_gather(const float4* __restrict__ feat,
                         const int* __restrict__ atom_num,
                         const int* __restrict__ offsets,
                         const int* __restrict__ label,
                         float4* __restrict__ out,
                         float* __restrict__ out_label,
                         int n) {
    __shared__ int off_s[RPB];
    __shared__ int cnt_s[RPB];
    int t = threadIdx.x;
    int rbase = blockIdx.x * RPB;
    if (t < RPB) {
        int r = rbase + t;
        if (r < n) {
            off_s[t] = offsets[r];
            cnt_s[t] = atom_num[r];
            out_label[r] = (float)label[r];   // harness reads d_out as f32
        } else {
            off_s[t] = 0;
            cnt_s[t] = 0;
        }
    }
    __syncthreads();

    // RPB*448 float4 elements per block, 256 threads -> 28 iters
    #pragma unroll 4
    for (int e = t; e < RPB * F4_PER_RES; e += 256) {
        int rl   = e / F4_PER_RES;           // residue within block
        int rem  = e - rl * F4_PER_RES;      // 0..447
        int slot = rem >> 5;                 // 0..13
        int r = rbase + rl;
        if (r < n) {
            float4 val = make_float4(0.f, 0.f, 0.f, 0.f);
            if (slot < cnt_s[rl]) {
                val = feat[(size_t)(off_s[rl] + slot) * F4_PER_ROW + (rem & 31)];
            }
            out[(size_t)r * F4_PER_RES + rem] = val;
        }
    }
}

extern "C" void kernel_launch(void* const* d_in, const int* in_sizes, int n_in,
                              void* d_out, int out_size, void* d_ws, size_t ws_size,
                              hipStream_t stream) {
    const float* feature = (const float*)d_in[0];
    const int* atom_num  = (const int*)d_in[1];
    const int* label     = (const int*)d_in[2];
    const int n = in_sizes[1];               // N_res = 100000

    float* out = (float*)d_out;
    float* out_label = out + (size_t)n * MAX_ATOMS * CCH;

    int* ws_offsets = (int*)d_ws;            // n ints
    int* ws_sums    = ws_offsets + n;        // nb ints

    int nb = (n + 255) / 256;                // 391 for n=100000 (<=512)
    k_block_sums<<<nb, 256, 0, stream>>>(atom_num, n, ws_sums);
    k_scan_sums<<<1, 512, 0, stream>>>(ws_sums, nb);
    k_offsets<<<nb, 256, 0, stream>>>(atom_num, n, ws_sums, ws_offsets);

    int gb = (n + RPB - 1) / RPB;            // 6250 blocks
    k_gather<<<gb, 256, 0, stream>>>((const float4*)feature, atom_num,
                                     ws_offsets, label,
                                     (float4*)out, out_label, n);
}

// Round 2
// 219.632 us; speedup vs baseline: 1.0326x; 1.0326x over previous
//
#include <hip/hip_runtime.h>

// Ragged gather-to-padded for SparseConvUnet preprocessing.
// feature: [Nrows, 128] f32 packed; atom_num: [N] int32 in [0,14);
// out = concat( padded [N,14,128] f32 (zero where slot>=atom_num), label as f32 [N] ).

#define MAX_ATOMS 14
#define CCH 128
#define F4_PER_ROW 32                       // 128 floats = 32 float4
#define F4_PER_RES (MAX_ATOMS * F4_PER_ROW) // 448
#define RPB 16                              // residues per gather block
#define ITERS ((RPB * F4_PER_RES) / 256)    // 28

typedef float f32x4 __attribute__((ext_vector_type(4)));

// ---- scan stage 1: per-256-residue block — local exclusive prefix + block total ----
__global__ void k_local_scan(const int* __restrict__ atom_num, int n,
                             int* __restrict__ local_off,   // [n]
                             int* __restrict__ sums) {      // [nb]
    __shared__ int lds[256];
    int t = threadIdx.x;
    int r = blockIdx.x * 256 + t;
    int v = (r < n) ? atom_num[r] : 0;
    lds[t] = v;
    __syncthreads();
    for (int d = 1; d < 256; d <<= 1) {
        int add = (t >= d) ? lds[t - d] : 0;
        __syncthreads();
        lds[t] += add;
        __syncthreads();
    }
    if (r < n) local_off[r] = lds[t] - v;    // exclusive within block
    if (t == 255) sums[blockIdx.x] = lds[255];
}

// ---- scan stage 2: single-block exclusive scan of block sums (nb<=512) ----
__global__ void k_scan_sums(int* __restrict__ sums, int nb) {
    __shared__ int lds[512];
    int t = threadIdx.x;
    int v = (t < nb) ? sums[t] : 0;
    lds[t] = v;
    __syncthreads();
    for (int d = 1; d < 512; d <<= 1) {
        int add = (t >= d) ? lds[t - d] : 0;
        __syncthreads();
        lds[t] += add;
        __syncthreads();
    }
    if (t < nb) sums[t] = lds[t] - v;        // exclusive
}

// ---- main gather: RPB residues per block, float4 coalesced, nontemporal ----
__global__ __launch_bounds__(256) void k_gather(
        const f32x4* __restrict__ feat,
        const int* __restrict__ atom_num,
        const int* __restrict__ local_off,
        const int* __restrict__ block_base,  // scanned sums, indexed by r>>8
        const int* __restrict__ label,
        f32x4* __restrict__ out,
        float* __restrict__ out_label,
        int n) {
    __shared__ int off_s[RPB];
    __shared__ int cnt_s[RPB];
    int t = threadIdx.x;
    int rbase = blockIdx.x * RPB;
    if (t < RPB) {
        int r = rbase + t;
        if (r < n) {
            // gather block lies fully inside one 256-residue scan block
            off_s[t] = block_base[rbase >> 8] + local_off[r];
            cnt_s[t] = atom_num[r];
            out_label[r] = (float)label[r];  // harness reads d_out as f32
        } else {
            off_s[t] = 0;
            cnt_s[t] = 0;
        }
    }
    __syncthreads();

    if (rbase + RPB <= n) {
        #pragma unroll 7
        for (int i = 0; i < ITERS; ++i) {
            int e    = t + i * 256;
            int rl   = e / F4_PER_RES;       // residue within block
            int rem  = e - rl * F4_PER_RES;  // 0..447
            int slot = rem >> 5;             // 0..13
            f32x4 val = (f32x4)0.f;
            if (slot < cnt_s[rl]) {
                val = __builtin_nontemporal_load(
                    &feat[(size_t)(off_s[rl] + slot) * F4_PER_ROW + (rem & 31)]);
            }
            __builtin_nontemporal_store(val,
                &out[(size_t)rbase * F4_PER_RES + e]);
        }
    } else {
        for (int i = 0; i < ITERS; ++i) {
            int e    = t + i * 256;
            int rl   = e / F4_PER_RES;
            int rem  = e - rl * F4_PER_RES;
            int slot = rem >> 5;
            if (rbase + rl < n) {
                f32x4 val = (f32x4)0.f;
                if (slot < cnt_s[rl]) {
                    val = __builtin_nontemporal_load(
                        &feat[(size_t)(off_s[rl] + slot) * F4_PER_ROW + (rem & 31)]);
                }
                __builtin_nontemporal_store(val,
                    &out[(size_t)rbase * F4_PER_RES + e]);
            }
        }
    }
}

extern "C" void kernel_launch(void* const* d_in, const int* in_sizes, int n_in,
                              void* d_out, int out_size, void* d_ws, size_t ws_size,
                              hipStream_t stream) {
    const float* feature = (const float*)d_in[0];
    const int* atom_num  = (const int*)d_in[1];
    const int* label     = (const int*)d_in[2];
    const int n = in_sizes[1];               // N_res = 100000

    float* out = (float*)d_out;
    float* out_label = out + (size_t)n * MAX_ATOMS * CCH;

    int* ws_local = (int*)d_ws;              // n ints: local exclusive prefix
    int* ws_sums  = ws_local + n;            // nb ints: block bases

    int nb = (n + 255) / 256;                // 391 for n=100000 (<=512)
    k_local_scan<<<nb, 256, 0, stream>>>(atom_num, n, ws_local, ws_sums);
    k_scan_sums<<<1, 512, 0, stream>>>(ws_sums, nb);

    int gb = (n + RPB - 1) / RPB;            // 6250 blocks
    k_gather<<<gb, 256, 0, stream>>>((const f32x4*)feature, atom_num,
                                     ws_local, ws_sums, label,
                                     (f32x4*)out, out_label, n);
}

// Round 3
// 218.305 us; speedup vs baseline: 1.0389x; 1.0061x over previous
//
#include <hip/hip_runtime.h>

// Ragged gather-to-padded for SparseConvUnet preprocessing.
// feature: [Nrows, 128] f32 packed; atom_num: [N] int32 in [0,14);
// out = concat( padded [N,14,128] f32 (zero where slot>=atom_num), label as f32 [N] ).
//
// 2-kernel structure: k_sums (per-256-chunk atom totals, 391 blocks) then
// k_gather, whose prologue derives its base offset from the chunk sums
// (L2-hot ~1.5KB) — no per-residue offset intermediate, one less launch.

#define MAX_ATOMS 14
#define CCH 128
#define F4_PER_ROW 32                       // 128 floats = 32 float4
#define F4_PER_RES (MAX_ATOMS * F4_PER_ROW) // 448 = 7*64 -> wave-aligned rows
#define RPB 16                              // residues per gather block
#define ITERS ((RPB * F4_PER_RES) / 256)    // 28

typedef float f32x4 __attribute__((ext_vector_type(4)));

// ---- kernel 1: per-256-residue chunk sums ----
__global__ __launch_bounds__(256) void k_sums(const int* __restrict__ atom_num,
                                              int n, int* __restrict__ sums) {
    __shared__ int lds[256];
    int t = threadIdx.x;
    int r = blockIdx.x * 256 + t;
    lds[t] = (r < n) ? atom_num[r] : 0;
    __syncthreads();
    for (int d = 128; d > 0; d >>= 1) {
        if (t < d) lds[t] += lds[t + d];
        __syncthreads();
    }
    if (t == 0) sums[blockIdx.x] = lds[0];
}

// ---- kernel 2: gather (computes its own offsets from chunk sums) ----
__global__ __launch_bounds__(256) void k_gather(
        const f32x4* __restrict__ feat,
        const int* __restrict__ atom_num,
        const int* __restrict__ sums,      // [nb] chunk totals
        const int* __restrict__ label,
        f32x4* __restrict__ out,
        float* __restrict__ out_label,
        int n) {
    __shared__ int red[256];
    __shared__ int off_s[RPB];
    __shared__ int cnt_s[RPB];
    int t = threadIdx.x;
    int rbase = blockIdx.x * RPB;
    int c      = rbase >> 8;               // scan chunk index
    int j0     = rbase & 255;              // residue offset within chunk
    int chunk0 = c << 8;

    // base = sum_{j<c} sums[j] + sum_{i<j0} atom_num[chunk0+i]   (all L2-hot)
    int part = 0;
    for (int j = t; j < c; j += 256) part += sums[j];        // <=2 steps
    if (t < j0) part += atom_num[chunk0 + t];                // j0<=240, 1 step
    red[t] = part;
    __syncthreads();
    for (int d = 128; d > 0; d >>= 1) {
        if (t < d) red[t] += red[t + d];
        __syncthreads();
    }
    int base = red[0];

    if (t < RPB) {
        int r = rbase + t;
        cnt_s[t] = (r < n) ? atom_num[r] : 0;
        if (r < n) out_label[r] = (float)label[r];  // harness reads d_out as f32
    }
    __syncthreads();
    if (t < RPB) {
        int o = base;
        #pragma unroll
        for (int i = 0; i < RPB; ++i) o += (i < t) ? cnt_s[i] : 0;
        off_s[t] = o;
    }
    __syncthreads();

    if (rbase + RPB <= n) {
        #pragma unroll 7
        for (int i = 0; i < ITERS; ++i) {
            int e    = t + i * 256;
            int rl   = e / F4_PER_RES;       // residue within block
            int rem  = e - rl * F4_PER_RES;  // 0..447
            int slot = rem >> 5;             // 0..13
            f32x4 val = (f32x4)0.f;
            if (slot < cnt_s[rl]) {
                val = __builtin_nontemporal_load(
                    &feat[(size_t)(off_s[rl] + slot) * F4_PER_ROW + (rem & 31)]);
            }
            __builtin_nontemporal_store(val,
                &out[(size_t)rbase * F4_PER_RES + e]);
        }
    } else {
        for (int i = 0; i < ITERS; ++i) {
            int e    = t + i * 256;
            int rl   = e / F4_PER_RES;
            int rem  = e - rl * F4_PER_RES;
            int slot = rem >> 5;
            if (rbase + rl < n) {
                f32x4 val = (f32x4)0.f;
                if (slot < cnt_s[rl]) {
                    val = __builtin_nontemporal_load(
                        &feat[(size_t)(off_s[rl] + slot) * F4_PER_ROW + (rem & 31)]);
                }
                __builtin_nontemporal_store(val,
                    &out[(size_t)rbase * F4_PER_RES + e]);
            }
        }
    }
}

extern "C" void kernel_launch(void* const* d_in, const int* in_sizes, int n_in,
                              void* d_out, int out_size, void* d_ws, size_t ws_size,
                              hipStream_t stream) {
    const float* feature = (const float*)d_in[0];
    const int* atom_num  = (const int*)d_in[1];
    const int* label     = (const int*)d_in[2];
    const int n = in_sizes[1];               // N_res = 100000

    float* out = (float*)d_out;
    float* out_label = out + (size_t)n * MAX_ATOMS * CCH;

    int* ws_sums = (int*)d_ws;               // nb ints

    int nb = (n + 255) / 256;                // 391 for n=100000
    k_sums<<<nb, 256, 0, stream>>>(atom_num, n, ws_sums);

    int gb = (n + RPB - 1) / RPB;            // 6250 blocks
    k_gather<<<gb, 256, 0, stream>>>((const f32x4*)feature, atom_num,
                                     ws_sums, label,
                                     (f32x4*)out, out_label, n);
}